// Round 6
// baseline (281.657 us; speedup 1.0000x reference)
//
#include <hip/hip_runtime.h>

#define NB 4
#define SEQ 4096
#define DM 1024
#define DF 64

typedef unsigned short u16;
typedef unsigned int u32;
typedef __attribute__((ext_vector_type(8))) _Float16 half8;        // 8 f16 = 4 VGPR (MFMA A/B frag)
typedef __attribute__((ext_vector_type(8))) unsigned short ushort8;
typedef __attribute__((ext_vector_type(4))) float f32x4;           // MFMA C/D frag

__device__ __forceinline__ u16 f2h(float f) {
    union { _Float16 h; u16 u; } v; v.h = (_Float16)f; return v.u;
}

#define MFMAH(a, b, c) __builtin_amdgcn_mfma_f32_16x16x32_f16(a, b, c, 0, 0, 0)

// ---------------- W prep: convert fp32 W to f16 -----------------------------
__global__ __launch_bounds__(256) void wprep_kernel(
    const float* __restrict__ W0, const float* __restrict__ W1, const float* __restrict__ W2,
    u16* __restrict__ Wh)
{
    int i = blockIdx.x * 256 + threadIdx.x;            // 0 .. 3*65536-1
    const float* W = (i < 65536) ? W0 : (i < 131072) ? W1 : W2;
    Wh[i] = f2h(W[i & 65535]);
}

// ---------------- Projection v7: X-direct, W-chunked, barrier-free k-loop ---
// grid (256, 3), block 256 (4 waves). Block owns 64 rows x 64 cols, full K.
// Wave w owns rows 16w..16w+15 (complete K -> no cross-wave reduction).
// X has ZERO cross-output reuse (N=64 handled in-register across 4 F-tiles),
// so X skips LDS entirely: each lane loads its A-frag straight from global
// (X[row][k+quad*8], 2x float4 -> cvt f16). Only W is LDS-staged, in 4
// chunks of K=256 (32 KB); next chunk's W prefetched to regs under compute.
// Inner 8 k-steps: NO barriers, 16 independent global loads per wave -> deep
// ILP hides HBM latency (R4 showed TLP/barrier levers don't; chain was the
// bottleneck). 8 barriers total vs 32.
// A-frag: A[m=lane&15][k=quad*8+j]; B-frag: B[k=quad*8+j][n=lane&15];
// D: col=lane&15, row=quad*4+reg  (HW-verified layout, same as attention).
#define WSTR 264   // W LDS row stride in u16 (256 + 8): b128 reads ~2-way = free
__global__ __launch_bounds__(256, 3) void proj7_kernel(
    const float* __restrict__ X0, const float* __restrict__ X1, const float* __restrict__ X2,
    const u16* __restrict__ Wh,
    const float* __restrict__ b0, const float* __restrict__ b1, const float* __restrict__ b2,
    u16* __restrict__ Oall)
{
    __shared__ u16 wlds[64 * WSTR];    // 33.8 KB; 3 blocks/CU fit (101 KB)

    const int t    = threadIdx.x;
    const int w    = t >> 6;
    const int lane = t & 63;
    const int m15  = lane & 15;
    const int quad = lane >> 4;
    const int y    = blockIdx.y;

    const float* X    = (y == 0) ? X0 : (y == 1) ? X1 : X2;
    const float* bias = (y == 0) ? b0 : (y == 1) ? b1 : b2;
    const u16*   wp   = Wh + y * 65536;
    u16*         O    = Oall + (size_t)y * (NB * SEQ * DF);

    const long r0 = (long)blockIdx.x * 64;
    const float* xrow = X + (r0 + 16 * w + m15) * DM;   // this lane's X row

    // W staging assignment: thread copies 8x ushort8 (rows i*8+wr2, col wc)
    const int wr2 = t >> 5;           // 0..7
    const int wc  = (t & 31) * 8;     // 0..248 (32 lanes cover a 256-col row)

    f32x4 acc[4];
#pragma unroll
    for (int F = 0; F < 4; ++F) acc[F] = (f32x4){0.f, 0.f, 0.f, 0.f};

    // prefetch chunk 0's W into regs
    ushort8 wreg[8];
#pragma unroll
    for (int i = 0; i < 8; ++i)
        wreg[i] = *(const ushort8*)(wp + (i * 8 + wr2) * DM + wc);

    for (int c = 0; c < 4; ++c) {              // 4 K-chunks of 256
        const int k0 = c * 256;
        __syncthreads();   // prior chunk's LDS readers done
#pragma unroll
        for (int i = 0; i < 8; ++i)
            *(ushort8*)&wlds[(i * 8 + wr2) * WSTR + wc] = wreg[i];
        __syncthreads();   // W chunk visible

        // prefetch next chunk's W (hidden under the k-loop)
        if (c + 1 < 4) {
#pragma unroll
            for (int i = 0; i < 8; ++i)
                wreg[i] = *(const ushort8*)(wp + (i * 8 + wr2) * DM + k0 + 256 + wc);
        }

        // ---- 8 k-steps of 32: barrier-free, deep-ILP global X loads ----
#pragma unroll
        for (int s = 0; s < 8; ++s) {
            const int kk = 32 * s + quad * 8;            // within-chunk k of this lane
            float4 x0 = *(const float4*)(xrow + k0 + kk);
            float4 x1 = *(const float4*)(xrow + k0 + kk + 4);
            half8 a;
            a[0] = (_Float16)x0.x; a[1] = (_Float16)x0.y;
            a[2] = (_Float16)x0.z; a[3] = (_Float16)x0.w;
            a[4] = (_Float16)x1.x; a[5] = (_Float16)x1.y;
            a[6] = (_Float16)x1.z; a[7] = (_Float16)x1.w;
#pragma unroll
            for (int F = 0; F < 4; ++F) {
                half8 b = *(const half8*)&wlds[(16 * F + m15) * WSTR + kk];
                acc[F] = MFMAH(a, b, acc[F]);
            }
        }
    }

    // ---- epilogue: bias + f16 store ----
#pragma unroll
    for (int F = 0; F < 4; ++F) {
        float bv = bias[16 * F + m15];
#pragma unroll
        for (int r = 0; r < 4; ++r)
            O[(r0 + 16 * w + 4 * quad + r) * DF + 16 * F + m15] = f2h(acc[F][r] + bv);
    }
}

// ---------------- MFMA flash attention (key-split, f16) ---------------------
// grid (64, NB, nsplit), block 256 (4 waves). Block covers 64 q rows; wave w
// owns q rows q0+16w..+15; blockIdx.z covers `ntiles` 64-key tiles.
// If norm==1 (nsplit==1): normalize in-kernel, write to Opart directly.
// Else: write unnormalized O + per-row (m,l) partials for the combine kernel.
#define KSTR 72          // padded LDS stride (shorts), keeps 16B align

__global__ __launch_bounds__(256) void attn_mfma_kernel(
    const u16* __restrict__ Qg, const u16* __restrict__ Kg, const u16* __restrict__ Vg,
    float* __restrict__ Opart, float* __restrict__ Mp, float* __restrict__ Lp,
    int ntiles, int norm)
{
    __shared__ u16 ks[64 * KSTR];        // K tile, row-major [key][d]
    __shared__ u16 vt[64 * KSTR];        // V tile TRANSPOSED [f][key]
    __shared__ u16 ps[4][16 * KSTR];     // per-wave P tile [q][key]

    const int t    = threadIdx.x;
    const int w    = t >> 6;
    const int lane = t & 63;
    const int m15  = lane & 15;
    const int quad = lane >> 4;
    const int b    = blockIdx.y;
    const int z    = blockIdx.z;
    const int q0   = blockIdx.x * 64;

    // Q fragments, resident for the whole kernel (direct from global, f16)
    const u16* qptr = Qg + ((long)(b * SEQ + q0 + 16 * w + m15)) * DF + quad * 8;
    half8 qa0 = *(const half8*)qptr;          // d 0..31 chunk
    half8 qa1 = *(const half8*)(qptr + 32);   // d 32..63 chunk

    f32x4 accO[4];
#pragma unroll
    for (int F = 0; F < 4; ++F) accO[F] = (f32x4){0.f, 0.f, 0.f, 0.f};
    float mrow[4] = {-1e30f, -1e30f, -1e30f, -1e30f};
    float lrow[4] = {0.f, 0.f, 0.f, 0.f};

    const long kvbase = ((long)b * SEQ + (long)z * ntiles * 64) * DF;
    const ushort4* kb4 = (const ushort4*)(Kg + kvbase);
    const ushort4* vb4 = (const ushort4*)(Vg + kvbase);

    // staging registers (software pipeline: global->reg ahead, reg->LDS at top)
    ushort4 kreg[4], vreg[4];
    const int krow  = t >> 4;          // K staging: rows krow, krow+16,32,48
    const int kcol4 = t & 15;
    const int vj0   = (t & 15) * 4;    // V transpose: keys vj0..vj0+3
    const int vf0   = (t >> 4) * 4;    // features vf0..vf0+3
#pragma unroll
    for (int c = 0; c < 4; ++c) {
        kreg[c] = kb4[(krow + 16 * c) * 16 + kcol4];
        vreg[c] = vb4[(vj0 + c) * 16 + (vf0 >> 2)];
    }

    for (int tile = 0; tile < ntiles; ++tile) {
        __syncthreads();   // prior tile's LDS readers done
#pragma unroll
        for (int c = 0; c < 4; ++c)    // K: raw f16 copy
            *(ushort4*)&ks[(krow + 16 * c) * KSTR + kcol4 * 4] = kreg[c];
        {                              // V: 4x4 in-register transpose
            ushort4 w0 = {vreg[0].x, vreg[1].x, vreg[2].x, vreg[3].x};
            ushort4 w1 = {vreg[0].y, vreg[1].y, vreg[2].y, vreg[3].y};
            ushort4 w2 = {vreg[0].z, vreg[1].z, vreg[2].z, vreg[3].z};
            ushort4 w3 = {vreg[0].w, vreg[1].w, vreg[2].w, vreg[3].w};
            *(ushort4*)&vt[(vf0 + 0) * KSTR + vj0] = w0;
            *(ushort4*)&vt[(vf0 + 1) * KSTR + vj0] = w1;
            *(ushort4*)&vt[(vf0 + 2) * KSTR + vj0] = w2;
            *(ushort4*)&vt[(vf0 + 3) * KSTR + vj0] = w3;
        }
        __syncthreads();   // staging visible

        if (tile + 1 < ntiles) {       // prefetch next tile (latency hidden by compute)
#pragma unroll
            for (int c = 0; c < 4; ++c) {
                kreg[c] = kb4[(tile + 1) * 1024 + (krow + 16 * c) * 16 + kcol4];
                vreg[c] = vb4[(tile + 1) * 1024 + (vj0 + c) * 16 + (vf0 >> 2)];
            }
        }

        // ---- QK^T: 4 key-subtiles x 2 d-chunks ----
        f32x4 S[4];
#pragma unroll
        for (int T = 0; T < 4; ++T) {
            const u16* kp = &ks[(16 * T + m15) * KSTR + quad * 8];
            half8 kb0 = *(const half8*)kp;
            half8 kb1 = *(const half8*)(kp + 32);
            S[T] = MFMAH(qa0, kb0, ((f32x4){0.f, 0.f, 0.f, 0.f}));
            S[T] = MFMAH(qa1, kb1, S[T]);
        }

        // ---- online softmax (rows 4*quad+r live in this quad) ----
        float mx[4], alpha[4], mn[4], psum[4];
#pragma unroll
        for (int T = 0; T < 4; ++T)
#pragma unroll
            for (int r = 0; r < 4; ++r) S[T][r] *= 0.125f;   // 1/sqrt(64)
#pragma unroll
        for (int r = 0; r < 4; ++r) {
            mx[r] = fmaxf(fmaxf(S[0][r], S[1][r]), fmaxf(S[2][r], S[3][r]));
#pragma unroll
            for (int s = 1; s < 16; s <<= 1) mx[r] = fmaxf(mx[r], __shfl_xor(mx[r], s));
            mn[r] = fmaxf(mrow[r], mx[r]);
            alpha[r] = __expf(mrow[r] - mn[r]);
            mrow[r] = mn[r];
            psum[r] = 0.f;
        }
#pragma unroll
        for (int T = 0; T < 4; ++T)
#pragma unroll
            for (int r = 0; r < 4; ++r) {
                float p = __expf(S[T][r] - mn[r]);
                psum[r] += p;
                ps[w][(4 * quad + r) * KSTR + 16 * T + m15] = f2h(p);
            }
#pragma unroll
        for (int r = 0; r < 4; ++r) {
#pragma unroll
            for (int s = 1; s < 16; s <<= 1) psum[r] += __shfl_xor(psum[r], s);
            lrow[r] = lrow[r] * alpha[r] + psum[r];
        }
#pragma unroll
        for (int F = 0; F < 4; ++F)
#pragma unroll
            for (int r = 0; r < 4; ++r) accO[F][r] *= alpha[r];

        // ---- PV: A = P (same-wave region, no barrier needed), B = Vt ----
        const u16* pp = &ps[w][m15 * KSTR + quad * 8];
        half8 pa0 = *(const half8*)pp;          // keys 0..31
        half8 pa1 = *(const half8*)(pp + 32);   // keys 32..63
#pragma unroll
        for (int F = 0; F < 4; ++F) {
            const u16* vp = &vt[(16 * F + m15) * KSTR + quad * 8];
            half8 vb0 = *(const half8*)vp;
            half8 vb1 = *(const half8*)(vp + 32);
            accO[F] = MFMAH(pa0, vb0, accO[F]);
            accO[F] = MFMAH(pa1, vb1, accO[F]);
        }
    }

    // ---- epilogue ----
    const long rowbase = (long)b * SEQ + q0 + 16 * w;
    if (norm) {
        float il[4];
#pragma unroll
        for (int r = 0; r < 4; ++r) il[r] = 1.f / lrow[r];
#pragma unroll
        for (int F = 0; F < 4; ++F)
#pragma unroll
            for (int r = 0; r < 4; ++r)
                Opart[(rowbase + 4 * quad + r) * DF + 16 * F + m15] = accO[F][r] * il[r];
    } else {
        float* Og = Opart + (size_t)z * (NB * SEQ * DF);
#pragma unroll
        for (int F = 0; F < 4; ++F)
#pragma unroll
            for (int r = 0; r < 4; ++r)
                Og[(rowbase + 4 * quad + r) * DF + 16 * F + m15] = accO[F][r];
        if (m15 == 0) {
#pragma unroll
            for (int r = 0; r < 4; ++r) {
                long rg = (long)z * (NB * SEQ) + rowbase + 4 * quad + r;
                Mp[rg] = mrow[r];
                Lp[rg] = lrow[r];
            }
        }
    }
}

// ---------------- combine: merge key-split flash partials -------------------
// out[row][f] = sum_g O_g[row][f] * e^{m_g - M} / (sum_g l_g * e^{m_g - M})
// 65536 threads: 4 threads/row, 16 features each.
__global__ __launch_bounds__(256) void combine_kernel(
    const float* __restrict__ Opart, const float* __restrict__ Mp, const float* __restrict__ Lp,
    float* __restrict__ out, int nsplit)
{
    const int tg  = blockIdx.x * 256 + threadIdx.x;
    const int row = tg >> 2;
    const int f0  = (tg & 3) * 16;

    float m = -1e30f;
    for (int g = 0; g < nsplit; ++g) m = fmaxf(m, Mp[g * (NB * SEQ) + row]);

    float l = 0.f;
    float4 o[4];
#pragma unroll
    for (int i = 0; i < 4; ++i) o[i] = (float4){0.f, 0.f, 0.f, 0.f};

    for (int g = 0; g < nsplit; ++g) {
        float e = __expf(Mp[g * (NB * SEQ) + row] - m);
        l += Lp[g * (NB * SEQ) + row] * e;
        const float* Op = Opart + ((long)g * (NB * SEQ) + row) * DF + f0;
#pragma unroll
        for (int i = 0; i < 4; ++i) {
            float4 v = *(const float4*)(Op + 4 * i);
            o[i].x += v.x * e; o[i].y += v.y * e; o[i].z += v.z * e; o[i].w += v.w * e;
        }
    }
    const float inv = 1.f / l;
#pragma unroll
    for (int i = 0; i < 4; ++i) {
        float4 v = {o[i].x * inv, o[i].y * inv, o[i].z * inv, o[i].w * inv};
        *(float4*)(out + (long)row * DF + f0 + 4 * i) = v;
    }
}

extern "C" void kernel_launch(void* const* d_in, const int* in_sizes, int n_in,
                              void* d_out, int out_size, void* d_ws, size_t ws_size,
                              hipStream_t stream) {
    (void)in_sizes; (void)n_in; (void)out_size;

    const float* X[3]  = { (const float*)d_in[0], (const float*)d_in[1], (const float*)d_in[2] };
    const float* W[3]  = { (const float*)d_in[3], (const float*)d_in[5], (const float*)d_in[7] };
    const float* Bv[3] = { (const float*)d_in[4], (const float*)d_in[6], (const float*)d_in[8] };

    char* wsb = (char*)d_ws;
    // workspace layout (bytes):
    const size_t P_BYTES  = (size_t)3 * NB * SEQ * DF * 2;   // 6,291,456  (Q,K,V f16)
    const size_t WH_BYTES = (size_t)3 * DF * DM * 2;         //   393,216  (Wh f16)
    const size_t ML_BYTES = (size_t)4 * NB * SEQ * 4;        //   262,144  (Mp / Lp each, max 4 splits)
    const size_t OP_BYTES = (size_t)NB * SEQ * DF * 4;       // 4,194,304  (per split)

    u16*   P   = (u16*)wsb;
    u16*   Wh  = (u16*)(wsb + P_BYTES);
    float* Mp  = (float*)(wsb + P_BYTES + WH_BYTES);
    float* Lp  = (float*)(wsb + P_BYTES + WH_BYTES + ML_BYTES);
    float* Op  = (float*)(wsb + P_BYTES + WH_BYTES + 2 * ML_BYTES);
    const size_t base_need = P_BYTES + WH_BYTES + 2 * ML_BYTES;

    int nsplit = 1;
    if (ws_size >= base_need + 4 * OP_BYTES)      nsplit = 4;
    else if (ws_size >= base_need + 2 * OP_BYTES) nsplit = 2;
    const int ntiles = (SEQ / 64) / nsplit;

    float* out = (float*)d_out;

    wprep_kernel<<<768, 256, 0, stream>>>(W[0], W[1], W[2], Wh);

    dim3 pgrid(NB * SEQ / 64, 3);
    proj7_kernel<<<pgrid, 256, 0, stream>>>(X[0], X[1], X[2], Wh,
                                            Bv[0], Bv[1], Bv[2], P);

    const size_t proj_elems = (size_t)NB * SEQ * DF;   // 1,048,576
    dim3 agrid(SEQ / 64, NB, nsplit);
    if (nsplit == 1) {
        attn_mfma_kernel<<<agrid, 256, 0, stream>>>(P, P + proj_elems, P + 2 * proj_elems,
                                                    out, Mp, Lp, ntiles, 1);
    } else {
        attn_mfma_kernel<<<agrid, 256, 0, stream>>>(P, P + proj_elems, P + 2 * proj_elems,
                                                    Op, Mp, Lp, ntiles, 0);
        combine_kernel<<<(NB * SEQ * 4) / 256, 256, 0, stream>>>(Op, Mp, Lp, out, nsplit);
    }
}